// Round 5
// baseline (329.433 us; speedup 1.0000x reference)
//
#include <hip/hip_runtime.h>
#include <hip/hip_bf16.h>

namespace {

constexpr int HEADS = 4;
constexpr int DQ    = 128;
constexpr int KVB   = 64;
constexpr int QB    = 192;             // 6 waves x 32 q-rows
constexpr int NQT   = 2;               // max len 383 -> 2 q-tiles of 192
constexpr int ROWF  = 3 * DQ * HEADS;  // 1536 floats per token row
constexpr int THREADS = 384;
constexpr float ALPHA = 0.08838834764831843f;
constexpr float INV_N = 1.0f / 512.0f;

typedef __bf16 bf16x8 __attribute__((ext_vector_type(8)));
typedef float  f32x16 __attribute__((ext_vector_type(16)));
typedef float  f32x4  __attribute__((ext_vector_type(4)));
typedef unsigned int u32;
typedef u32 u32x4 __attribute__((ext_vector_type(4)));

union FragU { u32x4 u; bf16x8 v; };

__device__ __forceinline__ u32 pkbf(float lo, float hi) {
  u32 r;
  asm("v_cvt_pk_bf16_f32 %0, %1, %2" : "=v"(r) : "v"(lo), "v"(hi));
  return r;
}

__device__ __forceinline__ u32 xor32(u32 x) {
  return (u32)__shfl_xor((int)x, 32, 64);
}

__device__ __forceinline__ float silu_p(float acc) {
  float s = acc * ALPHA;
  return s * INV_N * __builtin_amdgcn_rcpf(1.0f + __expf(-s));
}

#define GLOAD16(gp, lp) \
  __builtin_amdgcn_global_load_lds((const __attribute__((address_space(1))) u32*)(gp), \
                                   (__attribute__((address_space(3))) u32*)(lp), 16, 0, 0)

} // namespace

// Block = (qt, b, h): 6 waves, wave w owns q-rows qt*192 + 32w .. +31.
// Waves 0-3 stage (K: f32 dbuf LDS via global_load_lds; V: reg-staged pinned
// -> bf16 V^T LDS). Waves 4-5 are pure compute. Both qt blocks of a (b,h)
// are placed on the SAME XCD (blockIdx % 8) and adjacent dispatch slots so
// their concurrent K/V tile reads dedup in that XCD's L2.
__global__ __launch_bounds__(THREADS, 3)
void hstu_attn_kernel(const float* __restrict__ qkv,
                      const int* __restrict__ seq_offsets,
                      float* __restrict__ out,
                      int Z)
{
  // decode XCD-grouped flat index: bid = g + 8*(2*s + j)
  const int bid = blockIdx.x;
  const int g   = bid & 7;
  const int q   = bid >> 3;
  const int s   = q >> 1;
  const int j   = q & 1;
  const int grp = s * 8 + g;          // (b,h) group 0..511
  const int b   = grp >> 2;
  const int h   = grp & 3;
  const int qt  = 1 - j;              // heavy q-tile first
  if (b >= Z) return;

  const int off = seq_offsets[b];
  const int len = seq_offsets[b + 1] - off;
  if (qt * QB >= len) return;

  __shared__ __align__(16) float          Kf[2][KVB * DQ];  // 2 x 32 KB f32
  __shared__ __align__(16) unsigned short Vtb[KVB * DQ];    // 16 KB bf16 V^T

  const int t   = threadIdx.x;
  const int w   = t >> 6;
  const int l   = t & 63;
  const int l31 = l & 31;
  const int gg  = l >> 5;
  const int nb  = qt * QB + 32 * w;   // wave's first q row

  const float* __restrict__ base = qkv + (size_t)off * ROWF + h * (3 * DQ);

  // ---- K staging (waves 0-3): 32 gload calls, rows 2i,2i+1 per call ----
  const int khalf = l >> 5;
  const int kslot = (l & 31) >> 1;
  const int khb   = l & 1;

  auto issue_k = [&](int m0, int buf) {
    if (w < 4) {
#pragma unroll
      for (int jj = 0; jj < 8; jj++) {
        int i  = w * 8 + jj;
        int r  = 2 * i + khalf;
        int rm = m0 + r; rm = rm < len ? rm : len - 1;
        int Ls = kslot ^ ((r >> 1) & 15);
        GLOAD16(base + (size_t)rm * ROWF + DQ + Ls * 8 + khb * 4,
                (char*)Kf[buf] + i * 1024);
      }
    }
  };

  // ---- V staging (threads 0-255): rows (m0p, m0p+1), d-range d0v..+15 ----
  const int m0p = ((t & 255) >> 3) * 2;
  const int d0v = (t & 7) * 16;
  f32x4 vraw[8];

  auto issue_v = [&](int m0) {
    if (t < 256) {
      int r0 = m0 + m0p;     r0 = r0 < len ? r0 : len - 1;
      int r1 = m0 + m0p + 1; r1 = r1 < len ? r1 : len - 1;
      const f32x4* p0 = (const f32x4*)(base + (size_t)r0 * ROWF + 2 * DQ + d0v);
      const f32x4* p1 = (const f32x4*)(base + (size_t)r1 * ROWF + 2 * DQ + d0v);
#pragma unroll
      for (int i = 0; i < 4; i++) { vraw[i] = p0[i]; vraw[4 + i] = p1[i]; }
#pragma unroll
      for (int i = 0; i < 8; i++) asm volatile("" :: "v"(vraw[i]));  // pin
    }
  };

  auto pack_v = [&]() {
    if (t < 256) {
#pragma unroll
      for (int jj = 0; jj < 16; jj++) {
        int d   = d0v + jj;
        int row = d >> 1;
        int ch  = (d & 1) * 8 + (m0p >> 3);
        u32 pv  = pkbf(vraw[jj >> 2][jj & 3], vraw[4 + (jj >> 2)][jj & 3]);
        *(u32*)((char*)Vtb + row * 256 + ((ch ^ (row & 15)) << 4) + (m0p & 7) * 2) = pv;
      }
    }
  };

  issue_k(0, 0);
  issue_v(0);

  // ---- Q fragments (B-operand of swapped QK^T): lane holds Q[n=l31][d=16ks+8gg+j] ----
  bf16x8 qf[8];
  {
    int n  = nb + l31;
    int rq = n < len ? n : len - 1;   // clamped rows never stored
    const float* qrow = base + (size_t)rq * ROWF;
#pragma unroll
    for (int ks = 0; ks < 8; ks++) {
      int d = ks * 16 + gg * 8;
      f32x4 a0 = *(const f32x4*)(qrow + d);
      f32x4 a1 = *(const f32x4*)(qrow + d + 4);
      FragU u;
      u.u[0] = pkbf(a0[0], a0[1]);
      u.u[1] = pkbf(a0[2], a0[3]);
      u.u[2] = pkbf(a1[0], a1[1]);
      u.u[3] = pkbf(a1[2], a1[3]);
      qf[ks] = u.v;
    }
  }

  f32x16 Of[4];
#pragma unroll
  for (int i = 0; i < 4; i++)
#pragma unroll
    for (int r = 0; r < 16; r++) Of[i][r] = 0.0f;

  const int nkv = min((len + KVB - 1) >> 6, 3 * qt + 3);
  int cur = 0;

  for (int kvt = 0; kvt < nkv; kvt++) {
    const int m0 = kvt * KVB;

    pack_v();   // waves 0-3: vmcnt wait for vraw drains (older) K gloads too
    if (kvt + 1 < nkv) {
      issue_k(m0 + KVB, cur ^ 1);   // stays in flight across the barrier
      issue_v(m0 + KVB);
    }
    asm volatile("s_waitcnt lgkmcnt(0)" ::: "memory");
    __builtin_amdgcn_s_barrier();
    __builtin_amdgcn_sched_barrier(0);

    if (nb < len && m0 <= nb + 31) {   // wave-uniform causal skip
      const bool needmask = (m0 + KVB - 1) > nb;
      bf16x8 pa[4];

#pragma unroll
      for (int mt = 0; mt < 2; mt++) {
        f32x16 acc;
#pragma unroll
        for (int r = 0; r < 16; r++) acc[r] = 0.0f;
        const int mrow = mt * 32 + l31;
        const char* krow = (const char*)Kf[cur] + mrow * 512;
        const int   ksw  = (mrow >> 1) & 15;
        __builtin_amdgcn_s_setprio(1);
#pragma unroll
        for (int ks = 0; ks < 8; ks++) {
          int J = 2 * ks + gg;
          const f32x4* kp = (const f32x4*)(krow + ((J ^ ksw) << 5));
          f32x4 k0 = kp[0], k1 = kp[1];
          FragU u;
          u.u[0] = pkbf(k0[0], k0[1]);
          u.u[1] = pkbf(k0[2], k0[3]);
          u.u[2] = pkbf(k1[0], k1[1]);
          u.u[3] = pkbf(k1[2], k1[3]);
          // S^T = K * Q^T : lane holds n=l31, m=(r&3)+8(r>>2)+4gg+32mt
          acc = __builtin_amdgcn_mfma_f32_32x32x16_bf16(u.v, qf[ks], acc, 0, 0, 0);
        }
        __builtin_amdgcn_s_setprio(0);

        // silu + causal mask, pack bf16 pairs (m, m+1)
        u32 wk[8];
#pragma unroll
        for (int i = 0; i < 8; i++) {
          int r  = 2 * i;
          int mr = m0 + (r & 3) + 8 * (r >> 2) + 4 * gg + 32 * mt;
          float p0 = silu_p(acc[r]);
          float p1 = silu_p(acc[r + 1]);
          if (needmask) {
            int nglob = nb + l31;
            if (mr > nglob)     p0 = 0.0f;
            if (mr + 1 > nglob) p1 = 0.0f;
          }
          wk[i] = pkbf(p0, p1);
        }

        // redistribute halves lane<->lane+32 -> PV A-frags (k = 8gg + j)
        FragU fa, fb;
        {
          u32 t0 = xor32(wk[0]); u32 t2 = xor32(wk[2]);
          fa.u[0] = gg ? t2 : wk[0]; fa.u[2] = gg ? wk[2] : t0;
          u32 t1 = xor32(wk[1]); u32 t3 = xor32(wk[3]);
          fa.u[1] = gg ? t3 : wk[1]; fa.u[3] = gg ? wk[3] : t1;
          u32 t4 = xor32(wk[4]); u32 t6 = xor32(wk[6]);
          fb.u[0] = gg ? t6 : wk[4]; fb.u[2] = gg ? wk[6] : t4;
          u32 t5 = xor32(wk[5]); u32 t7 = xor32(wk[7]);
          fb.u[1] = gg ? t7 : wk[5]; fb.u[3] = gg ? wk[7] : t5;
        }
        pa[2 * mt]     = fa.v;
        pa[2 * mt + 1] = fb.v;
      }

      // ---- PV: O += P * V^T (A = P frags in reg, B = V^T from LDS) ----
      __builtin_amdgcn_s_setprio(1);
#pragma unroll
      for (int ks = 0; ks < 4; ks++) {
#pragma unroll
        for (int dt = 0; dt < 4; dt++) {
          int d   = dt * 32 + l31;
          int row = d >> 1;
          int ch  = (d & 1) * 8 + (2 * ks + gg);   // m>>3 = 2ks+gg
          bf16x8 vb = *(const bf16x8*)((char*)Vtb + row * 256 + ((ch ^ (row & 15)) << 4));
          Of[dt] = __builtin_amdgcn_mfma_f32_32x32x16_bf16(pa[ks], vb, Of[dt], 0, 0, 0);
        }
      }
      __builtin_amdgcn_s_setprio(0);
    }

    __builtin_amdgcn_sched_barrier(0);
    __builtin_amdgcn_s_barrier();   // frees Vtb and Kf[cur] for next tile's writes
    cur ^= 1;
  }

  // ---- epilogue: coalesced 4B stores for rows n < len ----
#pragma unroll
  for (int dt = 0; dt < 4; dt++) {
    int d = dt * 32 + l31;
#pragma unroll
    for (int r = 0; r < 16; r++) {
      int nloc = 4 * gg + (r & 3) + 8 * (r >> 2);
      int n = nb + nloc;
      if (n < len)
        out[(size_t)(off + n) * (HEADS * DQ) + h * DQ + d] = Of[dt][r];
    }
  }
}

extern "C" void kernel_launch(void* const* d_in, const int* in_sizes, int n_in,
                              void* d_out, int out_size, void* d_ws, size_t ws_size,
                              hipStream_t stream) {
  const float* qkv         = (const float*)d_in[0];
  const int*   seq_offsets = (const int*)d_in[1];
  float*       out         = (float*)d_out;
  int Z = in_sizes[1] - 1;
  dim3 grid(Z * HEADS * NQT);
  hstu_attn_kernel<<<grid, dim3(THREADS), 0, stream>>>(qkv, seq_offsets, out, Z);
}

// Round 6
// 97.719 us; speedup vs baseline: 3.3712x; 3.3712x over previous
//
#include <hip/hip_runtime.h>
#include <hip/hip_bf16.h>

namespace {

constexpr int HEADS = 4;
constexpr int DQ    = 128;
constexpr int KVB   = 64;
constexpr int QB    = 128;
constexpr int NQT   = 3;               // max len 383 -> 3 q-tiles of 128
constexpr int ROWF  = 3 * DQ * HEADS;  // 1536 floats per token row
constexpr float ALPHA = 0.08838834764831843f;
constexpr float INV_N = 1.0f / 512.0f;

typedef __bf16 bf16x8 __attribute__((ext_vector_type(8)));
typedef float  f32x16 __attribute__((ext_vector_type(16)));
typedef float  f32x4  __attribute__((ext_vector_type(4)));
typedef unsigned int u32;
typedef u32 u32x4 __attribute__((ext_vector_type(4)));

union FragU { u32x4 u; bf16x8 v; };

__device__ __forceinline__ u32 pkbf(float lo, float hi) {
  u32 r;
  asm("v_cvt_pk_bf16_f32 %0, %1, %2" : "=v"(r) : "v"(lo), "v"(hi));
  return r;
}

__device__ __forceinline__ u32 xor32(u32 x) {
  return (u32)__shfl_xor((int)x, 32, 64);
}

__device__ __forceinline__ float silu_p(float acc) {
  float s = acc * ALPHA;
  return s * INV_N * __builtin_amdgcn_rcpf(1.0f + __expf(-s));
}

#define GLOAD16(gp, lp) \
  __builtin_amdgcn_global_load_lds((const __attribute__((address_space(1))) u32*)(gp), \
                                   (__attribute__((address_space(3))) u32*)(lp), 16, 0, 0)

} // namespace

// Block = (qt, b, h): 4 waves, wave w owns q-rows qt*128 + 32w .. +31.
// K: f32 double-buffered LDS via global_load_lds (read-time cvt to bf16).
// V: reg-staged (pinned) -> packed bf16 V^T single-buffered LDS.
// The 3 q-tile blocks of a (b,h) are placed on the SAME XCD (bid % 8) in
// adjacent dispatch slots so their concurrent K/V reads dedup in L2.
__global__ __launch_bounds__(256, 2)
void hstu_attn_kernel(const float* __restrict__ qkv,
                      const int* __restrict__ seq_offsets,
                      float* __restrict__ out,
                      int Z)
{
  // decode XCD-grouped flat index: bid = g + 8*(3*s + j)
  const int bid = blockIdx.x;
  const int g   = bid & 7;
  const int q   = bid >> 3;
  const int s   = q / 3;
  const int j   = q - 3 * s;
  const int grp = s * 8 + g;            // (b,h) group 0..4*Z-1
  const int b   = (Z - 1) - (grp >> 2); // long sequences first
  const int h   = grp & 3;
  const int qt  = (NQT - 1) - j;        // heavy q-tile first
  if (b < 0) return;

  const int off = seq_offsets[b];
  const int len = seq_offsets[b + 1] - off;
  if (qt * QB >= len) return;

  __shared__ __align__(16) float          Kf[2][KVB * DQ];  // 2 x 32 KB f32
  __shared__ __align__(16) unsigned short Vtb[KVB * DQ];    // 16 KB bf16 V^T

  const int t   = threadIdx.x;
  const int w   = t >> 6;
  const int l   = t & 63;
  const int l31 = l & 31;
  const int gg  = l >> 5;
  const int nb  = qt * QB + 32 * w;   // wave's first q row

  const float* __restrict__ base = qkv + (size_t)off * ROWF + h * (3 * DQ);

  // ---- K staging: 32 gload calls (8/wave), rows 2i,2i+1 per call, 32B-slot swizzle ----
  const int khalf = l >> 5;          // row within pair
  const int kslot = (l & 31) >> 1;   // physical 32B slot 0..15
  const int khb   = l & 1;           // 16B half within slot

  auto issue_k = [&](int m0, int buf) {
#pragma unroll
    for (int jj = 0; jj < 8; jj++) {
      int i  = w * 8 + jj;
      int r  = 2 * i + khalf;
      int rm = m0 + r; rm = rm < len ? rm : len - 1;
      int Ls = kslot ^ ((r >> 1) & 15);          // logical 32B slot (involution)
      GLOAD16(base + (size_t)rm * ROWF + DQ + Ls * 8 + khb * 4,
              (char*)Kf[buf] + i * 1024);
    }
  };

  // ---- V staging: thread owns rows (m0p, m0p+1), d-range d0v..d0v+15 ----
  const int m0p = (t >> 3) * 2;
  const int d0v = (t & 7) * 16;
  f32x4 vraw[8];

  auto issue_v = [&](int m0) {
    int r0 = m0 + m0p;     r0 = r0 < len ? r0 : len - 1;
    int r1 = m0 + m0p + 1; r1 = r1 < len ? r1 : len - 1;
    const f32x4* p0 = (const f32x4*)(base + (size_t)r0 * ROWF + 2 * DQ + d0v);
    const f32x4* p1 = (const f32x4*)(base + (size_t)r1 * ROWF + 2 * DQ + d0v);
#pragma unroll
    for (int i = 0; i < 4; i++) { vraw[i] = p0[i]; vraw[4 + i] = p1[i]; }
#pragma unroll
    for (int i = 0; i < 8; i++) asm volatile("" :: "v"(vraw[i]));  // pin: no sinking
  };

  auto pack_v = [&]() {
#pragma unroll
    for (int jj = 0; jj < 16; jj++) {
      int d   = d0v + jj;
      int row = d >> 1;
      int ch  = (d & 1) * 8 + (m0p >> 3);
      u32 pv  = pkbf(vraw[jj >> 2][jj & 3], vraw[4 + (jj >> 2)][jj & 3]);
      *(u32*)((char*)Vtb + row * 256 + ((ch ^ (row & 15)) << 4) + (m0p & 7) * 2) = pv;
    }
  };

  issue_k(0, 0);
  issue_v(0);

  // ---- Q fragments (B-operand of swapped QK^T): lane holds Q[n=l31][d=16ks+8gg+j] ----
  bf16x8 qf[8];
  {
    int n  = nb + l31;
    int rq = n < len ? n : len - 1;   // clamped rows never stored
    const float* qrow = base + (size_t)rq * ROWF;
#pragma unroll
    for (int ks = 0; ks < 8; ks++) {
      int d = ks * 16 + gg * 8;
      f32x4 a0 = *(const f32x4*)(qrow + d);
      f32x4 a1 = *(const f32x4*)(qrow + d + 4);
      FragU u;
      u.u[0] = pkbf(a0[0], a0[1]);
      u.u[1] = pkbf(a0[2], a0[3]);
      u.u[2] = pkbf(a1[0], a1[1]);
      u.u[3] = pkbf(a1[2], a1[3]);
      qf[ks] = u.v;
    }
  }

  f32x16 Of[4];
#pragma unroll
  for (int i = 0; i < 4; i++)
#pragma unroll
    for (int r = 0; r < 16; r++) Of[i][r] = 0.0f;

  const int nkv = min((len + KVB - 1) >> 6, 2 * qt + 2);
  int cur = 0;

  for (int kvt = 0; kvt < nkv; kvt++) {
    const int m0 = kvt * KVB;

    pack_v();   // compiler vmcnt wait for vraw drains (older) K gloads too
    if (kvt + 1 < nkv) {
      issue_k(m0 + KVB, cur ^ 1);   // stays in flight across the barrier
      issue_v(m0 + KVB);
    }
    asm volatile("s_waitcnt lgkmcnt(0)" ::: "memory");
    __builtin_amdgcn_s_barrier();
    __builtin_amdgcn_sched_barrier(0);

    if (nb < len && m0 <= nb + 31) {   // wave-uniform causal skip
      const bool needmask = (m0 + KVB - 1) > nb;
      bf16x8 pa[4];

#pragma unroll
      for (int mt = 0; mt < 2; mt++) {
        f32x16 acc;
#pragma unroll
        for (int r = 0; r < 16; r++) acc[r] = 0.0f;
        const int mrow = mt * 32 + l31;
        const char* krow = (const char*)Kf[cur] + mrow * 512;
        const int   ksw  = (mrow >> 1) & 15;
        __builtin_amdgcn_s_setprio(1);
#pragma unroll
        for (int ks = 0; ks < 8; ks++) {
          int J = 2 * ks + gg;
          const f32x4* kp = (const f32x4*)(krow + ((J ^ ksw) << 5));
          f32x4 k0 = kp[0], k1 = kp[1];
          FragU u;
          u.u[0] = pkbf(k0[0], k0[1]);
          u.u[1] = pkbf(k0[2], k0[3]);
          u.u[2] = pkbf(k1[0], k1[1]);
          u.u[3] = pkbf(k1[2], k1[3]);
          // S^T = K * Q^T : lane holds n=l31, m=(r&3)+8(r>>2)+4gg+32mt
          acc = __builtin_amdgcn_mfma_f32_32x32x16_bf16(u.v, qf[ks], acc, 0, 0, 0);
        }
        __builtin_amdgcn_s_setprio(0);

        // silu + causal mask, pack bf16 pairs (m, m+1)
        u32 wk[8];
#pragma unroll
        for (int i = 0; i < 8; i++) {
          int r  = 2 * i;
          int mr = m0 + (r & 3) + 8 * (r >> 2) + 4 * gg + 32 * mt;
          float p0 = silu_p(acc[r]);
          float p1 = silu_p(acc[r + 1]);
          if (needmask) {
            int nglob = nb + l31;
            if (mr > nglob)     p0 = 0.0f;
            if (mr + 1 > nglob) p1 = 0.0f;
          }
          wk[i] = pkbf(p0, p1);
        }

        // redistribute halves lane<->lane+32 -> PV A-frags (k = 8gg + j)
        FragU fa, fb;
        {
          u32 t0 = xor32(wk[0]); u32 t2 = xor32(wk[2]);
          fa.u[0] = gg ? t2 : wk[0]; fa.u[2] = gg ? wk[2] : t0;
          u32 t1 = xor32(wk[1]); u32 t3 = xor32(wk[3]);
          fa.u[1] = gg ? t3 : wk[1]; fa.u[3] = gg ? wk[3] : t1;
          u32 t4 = xor32(wk[4]); u32 t6 = xor32(wk[6]);
          fb.u[0] = gg ? t6 : wk[4]; fb.u[2] = gg ? wk[6] : t4;
          u32 t5 = xor32(wk[5]); u32 t7 = xor32(wk[7]);
          fb.u[1] = gg ? t7 : wk[5]; fb.u[3] = gg ? wk[7] : t5;
        }
        pa[2 * mt]     = fa.v;
        pa[2 * mt + 1] = fb.v;
      }

      // ---- PV: O += P * V^T (A = P frags in reg, B = V^T from LDS) ----
      __builtin_amdgcn_s_setprio(1);
#pragma unroll
      for (int ks = 0; ks < 4; ks++) {
#pragma unroll
        for (int dt = 0; dt < 4; dt++) {
          int d   = dt * 32 + l31;
          int row = d >> 1;
          int ch  = (d & 1) * 8 + (2 * ks + gg);   // m>>3 = 2ks+gg
          bf16x8 vb = *(const bf16x8*)((char*)Vtb + row * 256 + ((ch ^ (row & 15)) << 4));
          Of[dt] = __builtin_amdgcn_mfma_f32_32x32x16_bf16(pa[ks], vb, Of[dt], 0, 0, 0);
        }
      }
      __builtin_amdgcn_s_setprio(0);
    }

    __builtin_amdgcn_sched_barrier(0);
    __builtin_amdgcn_s_barrier();   // frees Vtb and Kf[cur] for next tile's writes
    cur ^= 1;
  }

  // ---- epilogue: coalesced 4B stores for rows n < len ----
#pragma unroll
  for (int dt = 0; dt < 4; dt++) {
    int d = dt * 32 + l31;
#pragma unroll
    for (int r = 0; r < 16; r++) {
      int nloc = 4 * gg + (r & 3) + 8 * (r >> 2);
      int n = nb + nloc;
      if (n < len)
        out[(size_t)(off + n) * (HEADS * DQ) + h * DQ + d] = Of[dt][r];
    }
  }
}

extern "C" void kernel_launch(void* const* d_in, const int* in_sizes, int n_in,
                              void* d_out, int out_size, void* d_ws, size_t ws_size,
                              hipStream_t stream) {
  const float* qkv         = (const float*)d_in[0];
  const int*   seq_offsets = (const int*)d_in[1];
  float*       out         = (float*)d_out;
  int Z = in_sizes[1] - 1;
  dim3 grid(NQT * Z * HEADS);
  hstu_attn_kernel<<<grid, dim3(256), 0, stream>>>(qkv, seq_offsets, out, Z);
}